// Round 7
// baseline (1524.538 us; speedup 1.0000x reference)
//
#include <hip/hip_runtime.h>
#include <math.h>

#define N 512
#define H 12
#define CC 16      // C
#define CZ 128
#define CS 384
#define PQ 4
#define PV 8
#define CATR 2017
#define ATROW 520            // padded row stride of a_t (non-pow2)
#define ATPL  (H*ATROW)      // 6240 floats per i-plane

// ---------------------------------------------------------------------------
// Kernel 1: all projections. out[o,n] = sum_c W_sel[o][c] * s[c,n], o in [0,1152)
// ---------------------------------------------------------------------------
__global__ __launch_bounds__(256) void k_proj(
    const float* __restrict__ s,
    const float* __restrict__ Wq, const float* __restrict__ Wk, const float* __restrict__ Wv,
    const float* __restrict__ Wqp, const float* __restrict__ Wkp, const float* __restrict__ Wvp,
    float* __restrict__ proj)
{
    __shared__ float Wt[16][33];
    __shared__ float St[32][128];
    int t = threadIdx.x;
    int o0 = blockIdx.x * 16;
    int n0 = blockIdx.y * 128;
    const float* Wsrc; int orow;
    if (o0 < 192)      { Wsrc = Wq;  orow = o0; }
    else if (o0 < 384) { Wsrc = Wk;  orow = o0-192; }
    else if (o0 < 576) { Wsrc = Wv;  orow = o0-384; }
    else if (o0 < 720) { Wsrc = Wqp; orow = o0-576; }
    else if (o0 < 864) { Wsrc = Wkp; orow = o0-720; }
    else               { Wsrc = Wvp; orow = o0-864; }

    int og = t >> 6, nl = t & 63;
    float acc[4][2] = {};
    for (int c0 = 0; c0 < CS; c0 += 32) {
        __syncthreads();
        for (int k = 0; k < 2; k++) {
            int idx = t + k*256;
            int oo = idx >> 5, ccol = idx & 31;
            Wt[oo][ccol] = Wsrc[(orow+oo)*CS + c0 + ccol];
        }
        for (int k = 0; k < 4; k++) {
            int idx = t + k*256;
            int ccr = idx >> 5, nn4 = idx & 31;
            float4 v = *(const float4*)&s[(c0+ccr)*N + n0 + nn4*4];
            *(float4*)&St[ccr][nn4*4] = v;
        }
        __syncthreads();
        for (int kk = 0; kk < 32; kk++) {
            float sv0 = St[kk][nl], sv1 = St[kk][nl+64];
            #pragma unroll
            for (int r = 0; r < 4; r++) {
                float w = Wt[og*4+r][kk];
                acc[r][0] += w * sv0;
                acc[r][1] += w * sv1;
            }
        }
    }
    for (int r = 0; r < 4; r++) {
        int o = o0 + og*4 + r;
        proj[o*N + n0 + nl]      = acc[r][0];
        proj[o*N + n0 + 64 + nl] = acc[r][1];
    }
}

// ---------------------------------------------------------------------------
// Kernel 2: apply frames.
// ---------------------------------------------------------------------------
__global__ void k_frames(const float* __restrict__ proj,
                         const float* __restrict__ t_r, const float* __restrict__ t_t,
                         float* __restrict__ qg, float* __restrict__ kg, float* __restrict__ vg)
{
    int gid = blockIdx.x * blockDim.x + threadIdx.x;
    int n = gid & (N-1);
    int hp = gid >> 9;
    if (hp >= 192) return;
    const float* src; float* dst; int rowb, stride;
    if (hp < 48)      { src = proj + 576*N; dst = qg; rowb = hp;    stride = 48; }
    else if (hp < 96) { src = proj + 720*N; dst = kg; rowb = hp-48; stride = 48; }
    else              { src = proj + 864*N; dst = vg; rowb = hp-96; stride = 96; }
    float x0 = src[(rowb + 0*stride)*N + n];
    float x1 = src[(rowb + 1*stride)*N + n];
    float x2 = src[(rowb + 2*stride)*N + n];
    #pragma unroll
    for (int d = 0; d < 3; d++) {
        float r0 = t_r[(n*3+d)*3+0], r1 = t_r[(n*3+d)*3+1], r2 = t_r[(n*3+d)*3+2];
        dst[(rowb + d*stride)*N + n] = r0*x0 + r1*x1 + r2*x2 + t_t[n*3+d];
    }
}

// ---------------------------------------------------------------------------
// Kernel 2b: squared norms per (h,n).
// ---------------------------------------------------------------------------
__global__ void k_sq(const float* __restrict__ qg, const float* __restrict__ kg,
                     float* __restrict__ sq_q, float* __restrict__ sq_k)
{
    int gid = blockIdx.x * blockDim.x + threadIdx.x;
    int n = gid & (N-1);
    int sel = gid >> 9;
    int h = sel % H;
    const float* g = (sel < H) ? qg : kg;
    float* outp = (sel < H) ? sq_q : sq_k;
    float acc = 0.f;
    #pragma unroll
    for (int d = 0; d < 3; d++)
        #pragma unroll
        for (int p = 0; p < PQ; p++) {
            float v = g[(size_t)((d*H + h)*PQ + p)*N + n];
            acc += v*v;
        }
    outp[h*N + n] = acc;
}

// ---------------------------------------------------------------------------
// Kernel 3: logits -> a_t planes. Block = (i-tile 4, j-quarter 128), 128 thr.
// c-OUTER loop: per c reads z[c, i0:i0+4, j-quarter] (4x512B in 8KB window,
// unroll 8 -> deep in-flight reads). Epilogue adds qk + dist terms.
// ---------------------------------------------------------------------------
__global__ __launch_bounds__(128) void k_bias(
    const float* __restrict__ z, const float* __restrict__ proj,
    const float* __restrict__ qg, const float* __restrict__ kg,
    const float* __restrict__ sq_q, const float* __restrict__ sq_k,
    const float* __restrict__ Wb, const float* __restrict__ gamma,
    float* __restrict__ a_t)
{
    __shared__ float q_ls[192*4];    // q[(c*12+h)][ii]
    __shared__ float qg_ls[144*4];   // qg[row][ii]  (FIX R6: was 48*4, rows go to 143)
    __shared__ float sqq_ls[12*4];
    int t = threadIdx.x;             // 128
    int ii = t >> 5;                 // 0..3
    int jj = t & 31;
    int i0 = blockIdx.x * 4;
    int j0 = blockIdx.y * 128;
    int i = i0 + ii;
    int j4 = j0 + jj*4;
    const size_t NN = (size_t)N*N;
    const float w_l  = 0.57735026918962584f;   // sqrt(1/3)
    const float w_c2 = 0.11785113019775793f;   // sqrt(1/18)/2

    // stage small i-side operands
    for (int kk = 0; kk < 6; kk++) {
        int idx = kk*128 + t;
        if (idx < 768) { int r = idx >> 2, i2 = idx & 3; q_ls[idx] = proj[r*N + i0 + i2]; }
    }
    for (int kk = 0; kk < 5; kk++) {
        int idx = kk*128 + t;
        if (idx < 576) { int r = idx >> 2, i2 = idx & 3; qg_ls[idx] = qg[r*N + i0 + i2]; }
    }
    if (t < 48) { int r = t >> 2, i2 = t & 3; sqq_ls[t] = sq_q[r*N + i0 + i2]; }

    float ch[12];
    #pragma unroll
    for (int h = 0; h < 12; h++) {
        float g = gamma[h];
        float sp = (g > 20.f) ? g : log1pf(expf(g));
        ch[h] = sp * w_c2;
    }
    __syncthreads();

    // ---- c-loop: bias accumulation, 8 loads in flight
    float4 acc[12];
    #pragma unroll
    for (int h = 0; h < 12; h++) { acc[h].x=0.f; acc[h].y=0.f; acc[h].z=0.f; acc[h].w=0.f; }
    for (int cb = 0; cb < CZ; cb += 8) {
        float4 zb[8];
        #pragma unroll
        for (int u = 0; u < 8; u++)
            zb[u] = *(const float4*)&z[(size_t)(cb+u)*NN + (size_t)i*N + j4];
        #pragma unroll
        for (int u = 0; u < 8; u++) {
            int c = cb + u;
            #pragma unroll
            for (int h = 0; h < 12; h++) {
                float w = Wb[h*CZ + c];           // uniform -> s_load
                acc[h].x += w*zb[u].x; acc[h].y += w*zb[u].y;
                acc[h].z += w*zb[u].z; acc[h].w += w*zb[u].w;
            }
        }
    }

    // ---- epilogue: qk/4 + dist, then scale and store logits
    const float* kmat = proj + 192*N;
    #pragma unroll
    for (int h = 0; h < 12; h++) {
        float4 qk; qk.x=0.f; qk.y=0.f; qk.z=0.f; qk.w=0.f;
        #pragma unroll
        for (int c = 0; c < 16; c++) {
            int r = c*12 + h;
            float  qs = q_ls[r*4 + ii];
            float4 kv = *(const float4*)&kmat[(size_t)r*N + j4];
            qk.x += qs*kv.x; qk.y += qs*kv.y; qk.z += qs*kv.z; qk.w += qs*kv.w;
        }
        float4 g4; g4.x=0.f; g4.y=0.f; g4.z=0.f; g4.w=0.f;
        #pragma unroll
        for (int dp = 0; dp < 12; dp++) {
            int r = ((dp>>2)*12 + h)*4 + (dp&3);
            float  qgs = qg_ls[r*4 + ii];
            float4 kgv = *(const float4*)&kg[(size_t)r*N + j4];
            g4.x += qgs*kgv.x; g4.y += qgs*kgv.y; g4.z += qgs*kgv.z; g4.w += qgs*kgv.w;
        }
        float  sqq = sqq_ls[h*4 + ii];
        float4 sk  = *(const float4*)&sq_k[h*N + j4];
        float4 l;
        l.x = w_l*(acc[h].x + 0.25f*qk.x + ch[h]*(2.f*g4.x - sqq - sk.x));
        l.y = w_l*(acc[h].y + 0.25f*qk.y + ch[h]*(2.f*g4.y - sqq - sk.y));
        l.z = w_l*(acc[h].z + 0.25f*qk.z + ch[h]*(2.f*g4.z - sqq - sk.z));
        l.w = w_l*(acc[h].w + 0.25f*qk.w + ch[h]*(2.f*g4.w - sqq - sk.w));
        *(float4*)&a_t[(size_t)i*ATPL + h*ATROW + j4] = l;
    }
}

// ---------------------------------------------------------------------------
// Kernel 3b: softmax in a_t planes. Block per i; wave w handles h = 3w..3w+2.
// ---------------------------------------------------------------------------
__global__ __launch_bounds__(256) void k_softmax_t(float* __restrict__ a_t)
{
    int i = blockIdx.x;
    int w = threadIdx.x >> 6, l = threadIdx.x & 63;
    #pragma unroll
    for (int hh = 0; hh < 3; hh++) {
        int h = w*3 + hh;
        float* row = a_t + (size_t)i*ATPL + h*ATROW + l*8;
        float4 v0 = *(const float4*)row;
        float4 v1 = *(const float4*)(row + 4);
        float m = fmaxf(fmaxf(fmaxf(v0.x,v0.y),fmaxf(v0.z,v0.w)),
                        fmaxf(fmaxf(v1.x,v1.y),fmaxf(v1.z,v1.w)));
        for (int s = 32; s > 0; s >>= 1) m = fmaxf(m, __shfl_xor(m, s));
        v0.x = __expf(v0.x-m); v0.y = __expf(v0.y-m);
        v0.z = __expf(v0.z-m); v0.w = __expf(v0.w-m);
        v1.x = __expf(v1.x-m); v1.y = __expf(v1.y-m);
        v1.z = __expf(v1.z-m); v1.w = __expf(v1.w-m);
        float sm = v0.x+v0.y+v0.z+v0.w+v1.x+v1.y+v1.z+v1.w;
        for (int s = 32; s > 0; s >>= 1) sm += __shfl_xor(sm, s);
        float inv = 1.f/sm;
        v0.x*=inv; v0.y*=inv; v0.z*=inv; v0.w*=inv;
        v1.x*=inv; v1.y*=inv; v1.z*=inv; v1.w*=inv;
        *(float4*)row = v0;
        *(float4*)(row+4) = v1;
    }
}

// ---------------------------------------------------------------------------
// Kernel 4: o1. Block = (c-chunk 32, i-pair), grid (4,256), 192 threads.
// ---------------------------------------------------------------------------
__global__ __launch_bounds__(192) void k_o1_t(
    const float* __restrict__ z, const float* __restrict__ a_t, float* __restrict__ cat)
{
    __shared__ float zls[4*2*512];    // 16 KB
    int t = threadIdx.x;
    int ii = t / 96;
    int rem = t - ii*96;
    int h  = rem >> 3;
    int js = rem & 7;
    int c0 = blockIdx.x * 32;
    int i0 = blockIdx.y * 2;
    const size_t NN = (size_t)N*N;

    // a fragment in registers: j = js*4 + m*32, m = 0..15
    float4 areg[16];
    #pragma unroll
    for (int m = 0; m < 16; m++)
        areg[m] = *(const float4*)&a_t[(size_t)(i0+ii)*ATPL + h*ATROW + js*4 + m*32];

    float acc[32];
    #pragma unroll
    for (int c = 0; c < 32; c++) acc[c] = 0.f;

    #pragma unroll
    for (int cb = 0; cb < 32; cb += 4) {
        __syncthreads();
        for (int kk = 0; kk < 6; kk++) {
            int idx = kk*192 + t;
            if (idx < 1024) {
                int cu = idx >> 8, i2 = (idx >> 7) & 1, jf = (idx & 127) * 4;
                *(float4*)&zls[cu*1024 + i2*512 + jf] =
                    *(const float4*)&z[(size_t)(c0+cb+cu)*NN + (size_t)(i0+i2)*N + jf];
            }
        }
        __syncthreads();
        #pragma unroll
        for (int u = 0; u < 4; u++) {
            float s = 0.f;
            #pragma unroll
            for (int m = 0; m < 16; m++) {
                float4 zz = *(const float4*)&zls[u*1024 + ii*512 + js*4 + m*32];
                s += zz.x*areg[m].x + zz.y*areg[m].y + zz.z*areg[m].z + zz.w*areg[m].w;
            }
            acc[cb+u] += s;
        }
    }

    #pragma unroll
    for (int c = 0; c < 32; c++) {
        float v = acc[c];
        v += __shfl_xor(v, 1);
        v += __shfl_xor(v, 2);
        v += __shfl_xor(v, 4);
        if (js == 0)
            cat[(size_t)((c0+c)*H + h)*N + i0 + ii] = v;
    }
}

// ---------------------------------------------------------------------------
// Kernel 5: o2 + o3g. grid (12 h, 64 i-tiles of 8). 4-way j split. reads a_t.
// ---------------------------------------------------------------------------
__global__ __launch_bounds__(256) void k_o2o3g(
    const float* __restrict__ a_t, const float* __restrict__ proj, const float* __restrict__ vg,
    float* __restrict__ cat, float* __restrict__ o3g)
{
    __shared__ float ats[8*132];      // 4.2 KB
    __shared__ float vts[40*132];     // 21.1 KB
    int h = blockIdx.x, i0 = blockIdx.y*8;
    int t = threadIdx.x;
    int il = t & 7, rg = (t>>3)&7, jq = t>>6;
    const float* v = proj + 384*N;
    float acc[5] = {};
    for (int jc = 0; jc < 4; jc++) {
        __syncthreads();
        {   // a tile 8x128 float4: 1 per thread
            int ii = t >> 5, j4 = t & 31;
            *(float4*)&ats[ii*132 + j4*4] =
                *(const float4*)&a_t[(size_t)(i0+ii)*ATPL + h*ATROW + jc*128 + j4*4];
        }
        #pragma unroll
        for (int k = 0; k < 5; k++) {  // v/vg tile 40x128 float4
            int idx = t + k*256;
            int r = idx >> 5, j4 = idx & 31;
            const float* src = (r < 16) ? (v + (size_t)(r*H + h)*N)
                : (vg + (size_t)(((r-16)>>3)*96 + h*PV + ((r-16)&7))*N);
            *(float4*)&vts[r*132 + j4*4] = *(const float4*)&src[jc*128 + j4*4];
        }
        __syncthreads();
        #pragma unroll
        for (int s = 0; s < 8; s++) {
            int jo = jq*32 + s*4;
            float4 a4 = *(const float4*)&ats[il*132 + jo];
            #pragma unroll
            for (int r = 0; r < 5; r++) {
                float4 v4 = *(const float4*)&vts[(rg*5+r)*132 + jo];
                acc[r] += v4.x*a4.x + v4.y*a4.y + v4.z*a4.z + v4.w*a4.w;
            }
        }
    }
    __syncthreads();
    if (jq >= 2) {
        float* rb = &ats[((jq-2)*64 + (t & 63))*5];
        #pragma unroll
        for (int r = 0; r < 5; r++) rb[r] = acc[r];
    }
    __syncthreads();
    if (jq < 2) {
        const float* rb = &ats[(jq*64 + (t & 63))*5];
        #pragma unroll
        for (int r = 0; r < 5; r++) acc[r] += rb[r];
        if (jq == 1) {
            float* rb2 = &ats[640 + (t & 63)*5];
            #pragma unroll
            for (int r = 0; r < 5; r++) rb2[r] = acc[r];
        }
    }
    __syncthreads();
    if (jq == 0) {
        const float* rb2 = &ats[640 + t*5];
        #pragma unroll
        for (int r = 0; r < 5; r++) {
            float val = acc[r] + rb2[r];
            int row = rg*5 + r;
            if (row < 16) cat[(size_t)(1536 + row*H + h)*N + i0 + il] = val;
            else { int rr = row - 16;
                   o3g[(size_t)((rr>>3)*96 + h*PV + (rr&7))*N + i0 + il] = val; }
        }
    }
}

// ---------------------------------------------------------------------------
// Kernel 6: inverse frame transform -> cat rows 1728..2015
// ---------------------------------------------------------------------------
__global__ void k_o3(const float* __restrict__ o3g,
                     const float* __restrict__ t_r, const float* __restrict__ t_t,
                     float* __restrict__ cat)
{
    int gid = blockIdx.x*blockDim.x + threadIdx.x;
    int i = gid & (N-1), hp = gid >> 9;
    if (hp >= 96) return;
    float x0 = o3g[(size_t)(0*96 + hp)*N + i] - t_t[i*3+0];
    float x1 = o3g[(size_t)(1*96 + hp)*N + i] - t_t[i*3+1];
    float x2 = o3g[(size_t)(2*96 + hp)*N + i] - t_t[i*3+2];
    #pragma unroll
    for (int d = 0; d < 3; d++) {
        float o = t_r[(i*3+0)*3+d]*x0 + t_r[(i*3+1)*3+d]*x1 + t_r[(i*3+2)*3+d]*x2;
        cat[(size_t)(1728 + d*96 + hp)*N + i] = o;
    }
}

// ---------------------------------------------------------------------------
// Kernel 6b: o3_norm -> cat row 2016
// ---------------------------------------------------------------------------
__global__ void k_norm(float* __restrict__ cat)
{
    int i = blockIdx.x*blockDim.x + threadIdx.x;
    if (i >= N) return;
    float acc = 0.f;
    for (int r = 0; r < 288; r++) {
        float v = cat[(size_t)(1728+r)*N + i];
        acc += v*v;
    }
    cat[(size_t)2016*N + i] = sqrtf(acc);
}

// ---------------------------------------------------------------------------
// Kernel 7: final GEMM, split-K=4 with atomics.
// ---------------------------------------------------------------------------
__global__ __launch_bounds__(256) void k_final(
    const float* __restrict__ Ws, const float* __restrict__ bs,
    const float* __restrict__ cat, float* __restrict__ out)
{
    __shared__ float Wt[16*33];
    __shared__ float Ct[32*66];
    int o0 = blockIdx.x*16, n0 = blockIdx.y*64;
    int ks = blockIdx.z;
    int kbeg = ks*505, kend = min(CATR, kbeg+505);
    int t = threadIdx.x;
    int og = t >> 6, nl = t & 63;
    float acc[4] = {};
    for (int c0 = kbeg; c0 < kend; c0 += 32) {
        __syncthreads();
        for (int k = 0; k < 2; k++) {
            int idx = t + k*256;
            int oo = idx >> 5, ccol = idx & 31;
            int c = c0 + ccol;
            Wt[oo*33 + ccol] = (c < kend) ? Ws[(size_t)(o0+oo)*CATR + c] : 0.f;
        }
        for (int k = 0; k < 4; k++) {
            int idx = t + k*256;
            int ccr = idx >> 5, j2 = idx & 31;
            int c = c0 + ccr;
            float2 vv; vv.x = 0.f; vv.y = 0.f;
            if (c < kend) vv = *(const float2*)&cat[(size_t)c*N + n0 + j2*2];
            *(float2*)&Ct[ccr*66 + j2*2] = vv;
        }
        __syncthreads();
        int klim = min(32, kend - c0);
        for (int kk = 0; kk < klim; kk++) {
            float cv = Ct[kk*66 + nl];
            #pragma unroll
            for (int r = 0; r < 4; r++)
                acc[r] += Wt[(og*4+r)*33 + kk] * cv;
        }
    }
    #pragma unroll
    for (int r = 0; r < 4; r++) {
        int o = o0 + og*4 + r;
        float val = acc[r];
        if (ks == 0) val += bs[o];
        atomicAdd(&out[(size_t)o*N + n0 + nl], val);
    }
}

// ---------------------------------------------------------------------------
extern "C" void kernel_launch(void* const* d_in, const int* in_sizes, int n_in,
                              void* d_out, int out_size, void* d_ws, size_t ws_size,
                              hipStream_t stream)
{
    const float* s     = (const float*)d_in[0];
    const float* z     = (const float*)d_in[1];
    const float* t_r   = (const float*)d_in[2];
    const float* t_t   = (const float*)d_in[3];
    const float* Wq    = (const float*)d_in[4];
    const float* Wk    = (const float*)d_in[5];
    const float* Wv    = (const float*)d_in[6];
    const float* Wqp   = (const float*)d_in[7];
    const float* Wkp   = (const float*)d_in[8];
    const float* Wvp   = (const float*)d_in[9];
    const float* Wb    = (const float*)d_in[10];
    const float* gamma = (const float*)d_in[11];
    const float* Ws    = (const float*)d_in[12];
    const float* bs    = (const float*)d_in[13];
    float* out = (float*)d_out;

    float* ws   = (float*)d_ws;
    float* proj = ws;                       // 1152*512
    float* qg   = proj + 1152*N;            // 144*512
    float* kg   = qg   + 144*N;             // 144*512
    float* vg   = kg   + 144*N;             // 288*512
    float* sq_q = vg   + 288*N;             // 12*512
    float* sq_k = sq_q + H*N;               // 12*512
    float* o3g  = sq_k + H*N;               // 288*512
    float* a_t  = o3g  + 288*N;             // 512*6240 (logit/softmax planes)
    float* cat  = a_t  + (size_t)N*ATPL;    // 2017*512

    k_proj     <<<dim3(72,4),   256, 0, stream>>>(s, Wq, Wk, Wv, Wqp, Wkp, Wvp, proj);
    k_frames   <<<384,          256, 0, stream>>>(proj, t_r, t_t, qg, kg, vg);
    k_sq       <<<48,           256, 0, stream>>>(qg, kg, sq_q, sq_k);
    k_bias     <<<dim3(128,4),  128, 0, stream>>>(z, proj, qg, kg, sq_q, sq_k, Wb, gamma, a_t);
    k_softmax_t<<<512,          256, 0, stream>>>(a_t);
    k_o1_t     <<<dim3(4,256),  192, 0, stream>>>(z, a_t, cat);
    k_o2o3g    <<<dim3(12,64),  256, 0, stream>>>(a_t, proj, vg, cat, o3g);
    k_o3       <<<192,          256, 0, stream>>>(o3g, t_r, t_t, cat);
    k_norm     <<<2,            256, 0, stream>>>(cat);
    hipMemsetAsync(out, 0, (size_t)CS*N*sizeof(float), stream);
    k_final    <<<dim3(24,8,4), 256, 0, stream>>>(Ws, bs, cat, out);
}